// Round 1
// baseline (1287.883 us; speedup 1.0000x reference)
//
#include <hip/hip_runtime.h>

typedef unsigned short u16;
typedef unsigned int u32;
typedef __attribute__((ext_vector_type(8))) short short8;   // 8 bf16 (4 VGPRs) MFMA operand
typedef __attribute__((ext_vector_type(4))) float f32x4;    // MFMA accumulator

#define GLOBAL_AS __attribute__((address_space(1)))
#define LDS_AS __attribute__((address_space(3)))

// ---- helpers -------------------------------------------------------------
__device__ __forceinline__ u16 f2bf(float f) {           // RNE float->bf16
  u32 u = __float_as_uint(f);
  u += 0x7fffu + ((u >> 16) & 1u);
  return (u16)(u >> 16);
}
__device__ __forceinline__ float bflo(u32 u) { return __uint_as_float(u << 16); }
__device__ __forceinline__ float bfhi(u32 u) { return __uint_as_float(u & 0xffff0000u); }

__device__ __forceinline__ void gload_lds16(const void* g, void* l) {
  __builtin_amdgcn_global_load_lds((const GLOBAL_AS void*)g, (LDS_AS void*)l, 16, 0, 0);
}

// ---- kernel 1: fp32 -> bf16 conversion of X=[img;text], W=[Wq;Wk], bias --
// X bf16 lands in d_out second half; Wcat/bcat in d_ws.
__global__ __launch_bounds__(256) void convert_all(
    const float4* __restrict__ img4, const float4* __restrict__ text4,
    const float4* __restrict__ wq4, const float4* __restrict__ wk4,
    const float4* __restrict__ bq4, const float4* __restrict__ bk4,
    ushort4* __restrict__ xbf4, ushort4* __restrict__ wcat4,
    float4* __restrict__ bcat4) {
  size_t id = (size_t)blockIdx.x * 256 + threadIdx.x;
  if (id < 25165824) {                       // X: img (12582912 f4) then text
    float4 v = (id < 12582912) ? img4[id] : text4[id - 12582912];
    ushort4 r; r.x = f2bf(v.x); r.y = f2bf(v.y); r.z = f2bf(v.z); r.w = f2bf(v.w);
    xbf4[id] = r;
  } else if (id < 26214400) {                // W: Wq (524288 f4) then Wk
    size_t j = id - 25165824;
    float4 v = (j < 524288) ? wq4[j] : wk4[j - 524288];
    ushort4 r; r.x = f2bf(v.x); r.y = f2bf(v.y); r.z = f2bf(v.z); r.w = f2bf(v.w);
    wcat4[j] = r;
  } else {                                   // bias: bq (256 f4) then bk
    size_t j = id - 26214400;                // j < 512
    bcat4[j] = (j < 256) ? bq4[j] : bk4[j - 256];
  }
}

// ---- kernel 2: bf16 MFMA GEMM, 256x256 tile, 4-deep pipelined -------------
// C[m,n] = sum_d X[m,d]*W[n,d] + bias[n]; M=49152, N=2048, K=2048.
// 512 threads = 8 waves (2M x 4N), per-wave 128x64 output, BK=32.
// LDS: 4-buffer ring (128 KiB). Counted vmcnt(8) (never 0 in main loop),
// one raw s_barrier per K-tile. XOR bank-swizzle: linear LDS dest via
// global_load_lds + inverse-swizzled GLOBAL source + swizzled ds_read
// (both-sides-or-neither rule). XCD-aware block swizzle (1536 % 8 == 0).
// Output written bf16 into batch-interleaved QK layout in d_out first half:
//   batch block of 12 rows x 1024: [Q_i(0-2) K_i(3-5) Q_t(6-8) K_t(9-11)].
__global__ __launch_bounds__(512, 2) void gemm_qk(
    const u16* __restrict__ X, const u16* __restrict__ W,
    const float* __restrict__ bias, u16* __restrict__ QK) {
  __shared__ __align__(16) u16 As[4][8192];  // 4 bufs x 256 rows x 32 k = 64 KB
  __shared__ __align__(16) u16 Bs[4][8192];  // 64 KB

  const int t = threadIdx.x;
  const int lane = t & 63;
  const int wv = t >> 6;        // 0..7
  const int wm = wv >> 2;       // 0..1  (M wave)
  const int wn = wv & 3;        // 0..3  (N wave)
  const int fm = lane & 15;     // MFMA free index
  const int fq = lane >> 4;     // k-chunk (A/B) / row group (C)

  // XCD-aware bijective swizzle: 1536 blocks = 8 XCDs x 192
  const int swz = (blockIdx.x & 7) * 192 + (blockIdx.x >> 3);
  const int m0 = (swz >> 3) * 256;   // 192 m-tiles
  const int n0 = (swz & 7) * 256;    // 8 n-tiles (fast within XCD -> A reuse)

  // ---- staging addresses.  Per wave: 2 x 1KB instr per operand per tile.
  // LDS dest is linear (wave base + lane*16).  LDS slot (row, s) must hold
  // logical k-chunk  s ^ ((row>>1)&3)  (the read-side swizzle, involution),
  // so the GLOBAL source per lane is pre-swizzled by the same XOR.
  const int sr = lane >> 2;                                // row within 16-row grp
  const int sc = ((lane & 3) ^ ((lane >> 3) & 3)) * 8;     // swizzled k elems
  const u16* gA = X + (size_t)(m0 + wv * 32 + sr) * 2048 + sc;
  const u16* gB = W + (size_t)(n0 + wv * 32 + sr) * 2048 + sc;
  const int stgL = wv * 1024;                              // wave's LDS elem base

  // ---- compute-side LDS offsets (read swizzle: slot = fq ^ ((row>>1)&3)).
  // row = 16*const + fm  =>  (row>>1)&3 == (fm>>1)&3  (lane-constant).
  const int swz8 = (fq ^ ((fm >> 1) & 3)) * 8;
  const int aOff = (wm * 128 + fm) * 32 + swz8;  // + mi*512 (+2048 for mh=1)
  const int bOff = (wn * 64 + fm) * 32 + swz8;   // + nj*512

  const f32x4 zero = {0.f, 0.f, 0.f, 0.f};
  f32x4 acc[8][4];
#pragma unroll
  for (int i = 0; i < 8; i++)
#pragma unroll
    for (int j = 0; j < 4; j++) acc[i][j] = zero;

  auto STAGE = [&](int tile, int sb) {
    const u16* ga = gA + (size_t)tile * 32;
    const u16* gb = gB + (size_t)tile * 32;
    u16* la = &As[sb][stgL];
    u16* lb = &Bs[sb][stgL];
    gload_lds16(ga, la);
    gload_lds16(ga + 32768, la + 512);   // +16 rows
    gload_lds16(gb, lb);
    gload_lds16(gb + 32768, lb + 512);
  };

  auto COMPUTE = [&](int buf) {
    const u16* Ab = &As[buf][0];
    const u16* Bb = &Bs[buf][0];
    short8 a[4], b[4];
#pragma unroll
    for (int j = 0; j < 4; j++) b[j] = *(const short8*)&Bb[bOff + j * 512];
#pragma unroll
    for (int i = 0; i < 4; i++) a[i] = *(const short8*)&Ab[aOff + i * 512];
    __builtin_amdgcn_s_setprio(1);
#pragma unroll
    for (int i = 0; i < 4; i++)
#pragma unroll
      for (int j = 0; j < 4; j++)
        acc[i][j] = __builtin_amdgcn_mfma_f32_16x16x32_bf16(a[i], b[j], acc[i][j], 0, 0, 0);
    __builtin_amdgcn_s_setprio(0);
#pragma unroll
    for (int i = 0; i < 4; i++) a[i] = *(const short8*)&Ab[aOff + 2048 + i * 512];
    __builtin_amdgcn_s_setprio(1);
#pragma unroll
    for (int i = 0; i < 4; i++)
#pragma unroll
      for (int j = 0; j < 4; j++)
        acc[4 + i][j] = __builtin_amdgcn_mfma_f32_16x16x32_bf16(a[i], b[j], acc[4 + i][j], 0, 0, 0);
    __builtin_amdgcn_s_setprio(0);
  };

  // prologue: fill 3-deep
  STAGE(0, 0);
  STAGE(1, 1);
  STAGE(2, 2);

  // main loop: 64 K-tiles; stages lead compute by 3 tiles.
  // Steady state: 12 loads outstanding; vmcnt(8) lands the oldest tile.
  for (int kt = 0; kt < 61; ++kt) {
    asm volatile("s_waitcnt vmcnt(8)" ::: "memory");
    __builtin_amdgcn_s_barrier();
    asm volatile("" ::: "memory");
    STAGE(kt + 3, (kt + 3) & 3);
    COMPUTE(kt & 3);
  }
  // tail: drain 8 -> 4 -> 0
  asm volatile("s_waitcnt vmcnt(8)" ::: "memory");
  __builtin_amdgcn_s_barrier();
  asm volatile("" ::: "memory");
  COMPUTE(61 & 3);
  asm volatile("s_waitcnt vmcnt(4)" ::: "memory");
  __builtin_amdgcn_s_barrier();
  asm volatile("" ::: "memory");
  COMPUTE(62 & 3);
  asm volatile("s_waitcnt vmcnt(0)" ::: "memory");
  __builtin_amdgcn_s_barrier();
  asm volatile("" ::: "memory");
  COMPUTE(63 & 3);

  // epilogue: bias + bf16 convert + batch-interleaved scatter
  float bn[4];
#pragma unroll
  for (int j = 0; j < 4; j++) bn[j] = bias[n0 + wn * 64 + j * 16 + fm];

#pragma unroll
  for (int mi = 0; mi < 8; mi++) {
#pragma unroll
    for (int r = 0; r < 4; r++) {
      int mg = m0 + wm * 128 + mi * 16 + fq * 4 + r;  // C row = quad*4 + reg
      unsigned bb, idx, base;
      if (mg < 24576) { bb = (unsigned)mg / 3u; idx = (unsigned)mg - bb * 3u; base = 0u; }
      else { unsigned mt = (unsigned)mg - 24576u; bb = mt / 3u; idx = mt - bb * 3u; base = 6u; }
      size_t rowbase = (size_t)bb * 12288 + (size_t)(base + idx) * 1024;
#pragma unroll
      for (int j = 0; j < 4; j++) {
        int ng = n0 + wn * 64 + j * 16 + fm;          // C col = lane&15
        size_t pos = rowbase + ((ng & 1024) ? 3072 : 0) + (ng & 1023);
        QK[pos] = f2bf(acc[mi][j][r] + bn[j]);
      }
    }
  }
}

// ---- kernel 3: fused logits -> softmax -> j_lin -> bilinear -> outputs ----
// One block (256 thr) per batch. Reads its 12x1024 bf16 QK block (aliased with
// out_i region it later overwrites; ordering enforced by data deps + barrier).
__global__ __launch_bounds__(256) void fuse_out(
    const float* __restrict__ img, const float* __restrict__ text,
    const float* __restrict__ Wj, const float* __restrict__ bjp,
    const float* __restrict__ Wb, float* __restrict__ out) {
  const int t = threadIdx.x;
  const int lane = t & 63;
  const int wv = t >> 6;
  const int b = blockIdx.x;

  const uint2* qkp = (const uint2*)((const char*)out + (size_t)b * 24576);

  // each thread: 4 consecutive k of each of the 12 rows
  float R[12][4];
#pragma unroll
  for (int r = 0; r < 12; r++) {
    uint2 u = qkp[r * 256 + t];
    R[r][0] = bflo(u.x); R[r][1] = bfhi(u.x);
    R[r][2] = bflo(u.y); R[r][3] = bfhi(u.y);
  }
  float acc[27];
#pragma unroll
  for (int a = 0; a < 27; a++) acc[a] = 0.f;
#pragma unroll
  for (int q = 0; q < 3; q++)
#pragma unroll
    for (int s = 0; s < 3; s++)
#pragma unroll
      for (int j = 0; j < 4; j++) {
        acc[q * 3 + s]      += R[q][j]     * R[9 + s][j];  // it: Qi.Kt
        acc[9 + q * 3 + s]  += R[q][j]     * R[3 + s][j];  // ii: Qi.Ki
        acc[18 + q * 3 + s] += R[6 + q][j] * R[9 + s][j];  // tt: Qt.Kt
      }
  // wave allreduce then cross-wave via LDS
#pragma unroll
  for (int a = 0; a < 27; a++) {
    float v = acc[a];
#pragma unroll
    for (int off = 32; off > 0; off >>= 1) v += __shfl_xor(v, off, 64);
    acc[a] = v;
  }
  __shared__ float red[4][27];
  if (lane == 0) {
#pragma unroll
    for (int a = 0; a < 27; a++) red[wv][a] = acc[a];
  }
  __syncthreads();  // also fences: all QK loads precede the out stores below
  float S[27];
#pragma unroll
  for (int a = 0; a < 27; a++) S[a] = red[0][a] + red[1][a] + red[2][a] + red[3][a];

  // softmax over s, then * 1/sqrt(1024)
  float P[27];
#pragma unroll
  for (int m = 0; m < 3; m++)
#pragma unroll
    for (int q = 0; q < 3; q++) {
      int o0 = m * 9 + q * 3;
      float x = S[o0], y = S[o0 + 1], z = S[o0 + 2];
      float mx = fmaxf(x, fmaxf(y, z));
      float e0 = __expf(x - mx), e1 = __expf(y - mx), e2 = __expf(z - mx);
      float inv = 0.03125f / (e0 + e1 + e2);
      P[o0] = e0 * inv; P[o0 + 1] = e1 * inv; P[o0 + 2] = e2 * inv;
    }
  // j_lin on each map: J[map][q][o] = bj[o] + sum_s Wj[o,s]*P[map][q][s]
  float J[3][3][3];
#pragma unroll
  for (int m = 0; m < 3; m++)
#pragma unroll
    for (int q = 0; q < 3; q++)
#pragma unroll
      for (int o = 0; o < 3; o++)
        J[m][q][o] = bjp[o] + Wj[o * 3 + 0] * P[m * 9 + q * 3 + 0]
                            + Wj[o * 3 + 1] * P[m * 9 + q * 3 + 1]
                            + Wj[o * 3 + 2] * P[m * 9 + q * 3 + 2];
  // bilinear: ai = B(j_it, j_ii), at = B(j_it, j_tt)
  float ai[3][3], at[3][3];
#pragma unroll
  for (int q = 0; q < 3; q++)
#pragma unroll
    for (int o = 0; o < 3; o++) {
      float s1 = 0.f, s2 = 0.f;
#pragma unroll
      for (int i = 0; i < 3; i++) {
        float a1 = J[0][q][i];
#pragma unroll
        for (int j = 0; j < 3; j++) {
          float w = Wb[(o * 3 + i) * 3 + j];
          s1 += a1 * w * J[1][q][j];
          s2 += a1 * w * J[2][q][j];
        }
      }
      ai[q][o] = s1; at[q][o] = s2;
    }

  // outputs: out_i[q,d] = sum_s ai[q][s]*img[s,d] (fp32 inputs), same for text
  const float4* im4 = (const float4*)(img + (size_t)b * 6144);
  const float4* tx4 = (const float4*)(text + (size_t)b * 6144);
  float4* oi4 = (float4*)out + (size_t)b * 1536;
  float4* ot4 = (float4*)out + 12582912 + (size_t)b * 1536;
#pragma unroll
  for (int rep = 0; rep < 2; rep++) {
    int col = rep * 256 + t;
    float4 x0 = im4[col], x1 = im4[512 + col], x2 = im4[1024 + col];
    float4 y0 = tx4[col], y1 = tx4[512 + col], y2 = tx4[1024 + col];
#pragma unroll
    for (int q = 0; q < 3; q++) {
      float4 o1, o2;
      o1.x = ai[q][0] * x0.x + ai[q][1] * x1.x + ai[q][2] * x2.x;
      o1.y = ai[q][0] * x0.y + ai[q][1] * x1.y + ai[q][2] * x2.y;
      o1.z = ai[q][0] * x0.z + ai[q][1] * x1.z + ai[q][2] * x2.z;
      o1.w = ai[q][0] * x0.w + ai[q][1] * x1.w + ai[q][2] * x2.w;
      oi4[q * 512 + col] = o1;
      o2.x = at[q][0] * y0.x + at[q][1] * y1.x + at[q][2] * y2.x;
      o2.y = at[q][0] * y0.y + at[q][1] * y1.y + at[q][2] * y2.y;
      o2.z = at[q][0] * y0.z + at[q][1] * y1.z + at[q][2] * y2.z;
      o2.w = at[q][0] * y0.w + at[q][1] * y1.w + at[q][2] * y2.w;
      ot4[q * 512 + col] = o2;
    }
  }
}

// ---- launch ---------------------------------------------------------------
extern "C" void kernel_launch(void* const* d_in, const int* in_sizes, int n_in,
                              void* d_out, int out_size, void* d_ws, size_t ws_size,
                              hipStream_t stream) {
  const float* img  = (const float*)d_in[0];
  const float* text = (const float*)d_in[1];
  const float* Wq   = (const float*)d_in[2];
  const float* bq   = (const float*)d_in[3];
  const float* Wk   = (const float*)d_in[4];
  const float* bk   = (const float*)d_in[5];
  const float* Wj   = (const float*)d_in[6];
  const float* bj   = (const float*)d_in[7];
  const float* Wbil = (const float*)d_in[8];
  float* out = (float*)d_out;

  // workspace: Wcat bf16 (8,388,608 B) + bcat f32 (8 KB)  => needs ~8.4 MB
  u16* Wcat = (u16*)d_ws;
  float* bcat = (float*)((char*)d_ws + 8388608);
  // d_out second half hosts X=[img;text] bf16; first half hosts QK bf16
  u16* Xbf = (u16*)(out + 50331648);
  u16* QK  = (u16*)out;

  convert_all<<<102402, 256, 0, stream>>>(
      (const float4*)img, (const float4*)text, (const float4*)Wq,
      (const float4*)Wk, (const float4*)bq, (const float4*)bk,
      (ushort4*)Xbf, (ushort4*)Wcat, (float4*)bcat);

  // 1536 blocks = 192 m-tiles x 8 n-tiles (swizzled in-kernel, XCD-aware)
  gemm_qk<<<1536, 512, 0, stream>>>(Xbf, Wcat, bcat, QK);

  fuse_out<<<8192, 256, 0, stream>>>(img, text, Wj, bj, Wbil, out);
}

// Round 2
// 1223.554 us; speedup vs baseline: 1.0526x; 1.0526x over previous
//
#include <hip/hip_runtime.h>

typedef unsigned short u16;
typedef unsigned int u32;
typedef __attribute__((ext_vector_type(8))) short short8;   // 8 bf16 (4 VGPRs) MFMA operand
typedef __attribute__((ext_vector_type(4))) float f32x4;    // MFMA accumulator

#define GLOBAL_AS __attribute__((address_space(1)))
#define LDS_AS __attribute__((address_space(3)))

// ---- helpers -------------------------------------------------------------
__device__ __forceinline__ u16 f2bf(float f) {           // RNE float->bf16
  u32 u = __float_as_uint(f);
  u += 0x7fffu + ((u >> 16) & 1u);
  return (u16)(u >> 16);
}
__device__ __forceinline__ float bflo(u32 u) { return __uint_as_float(u << 16); }
__device__ __forceinline__ float bfhi(u32 u) { return __uint_as_float(u & 0xffff0000u); }

__device__ __forceinline__ void gload_lds16(const void* g, void* l) {
  __builtin_amdgcn_global_load_lds((const GLOBAL_AS void*)g, (LDS_AS void*)l, 16, 0, 0);
}

// ---- kernel 1: fp32 -> bf16 conversion of X=[img;text], W=[Wq;Wk], bias --
__global__ __launch_bounds__(256) void convert_all(
    const float4* __restrict__ img4, const float4* __restrict__ text4,
    const float4* __restrict__ wq4, const float4* __restrict__ wk4,
    const float4* __restrict__ bq4, const float4* __restrict__ bk4,
    ushort4* __restrict__ xbf4, ushort4* __restrict__ wcat4,
    float4* __restrict__ bcat4) {
  size_t id = (size_t)blockIdx.x * 256 + threadIdx.x;
  if (id < 25165824) {                       // X: img (12582912 f4) then text
    float4 v = (id < 12582912) ? img4[id] : text4[id - 12582912];
    ushort4 r; r.x = f2bf(v.x); r.y = f2bf(v.y); r.z = f2bf(v.z); r.w = f2bf(v.w);
    xbf4[id] = r;
  } else if (id < 26214400) {                // W: Wq (524288 f4) then Wk
    size_t j = id - 25165824;
    float4 v = (j < 524288) ? wq4[j] : wk4[j - 524288];
    ushort4 r; r.x = f2bf(v.x); r.y = f2bf(v.y); r.z = f2bf(v.z); r.w = f2bf(v.w);
    wcat4[j] = r;
  } else {                                   // bias: bq (256 f4) then bk
    size_t j = id - 26214400;                // j < 512
    bcat4[j] = (j < 256) ? bq4[j] : bk4[j - 256];
  }
}

// ---- kernel 2: bf16 MFMA GEMM, 256x256 tile, BK=64, 4-phase/K-tile -------
// C[m,n] = sum_d X[m,d]*W[n,d] + bias[n]; M=49152, N=2048, K=2048.
// 512 threads = 8 waves (2M x 4N), per-wave 128x64 output.
// Per phase: {ds_read quadrant frags | stage one 16KB half-tile} -> barrier
// -> lgkmcnt(0) -> setprio(1) 16 MFMA setprio(0) -> vmcnt(4) -> barrier.
// Half-tiles interleaved (Aa = rows {0-63,128-191} etc.) so stage order
// matches consumption order; vmcnt(4) keeps last-2-phases' loads in flight,
// guarantees everything older is landed+globalized before its first read.
// LDS dbuf: tile t -> buf t&1.  XOR bank swizzle: linear gload_lds dest +
// inverse-swizzled global source + swizzled ds_read (both-sides rule).
// Output written bf16 into batch-interleaved QK layout in d_out first half.
__global__ __launch_bounds__(512, 2) void gemm_qk(
    const u16* __restrict__ X, const u16* __restrict__ W,
    const float* __restrict__ bias, u16* __restrict__ QK) {
  __shared__ __align__(16) u16 Al[2][16384];  // 2 x 256 rows x 64 k = 64 KB
  __shared__ __align__(16) u16 Bl[2][16384];  // 64 KB

  const int t = threadIdx.x;
  const int lane = t & 63;
  const int wv = t >> 6;        // 0..7
  const int wm = wv >> 2;       // 0..1  (M wave)
  const int wn = wv & 3;        // 0..3  (N wave)
  const int fm = lane & 15;     // MFMA free index
  const int fq = lane >> 4;     // k-chunk (A/B) / row group (C)
  const int l3 = lane >> 3;     // 0..7
  const int l7 = lane & 7;

  // XCD-aware bijective swizzle: 1536 blocks = 8 XCDs x 192
  const int swz = (blockIdx.x & 7) * 192 + (blockIdx.x >> 3);
  const int m0 = (swz >> 3) * 256;   // 192 m-tiles
  const int n0 = (swz & 7) * 256;    // 8 n-tiles (fast within XCD -> A reuse)

  // ---- staging addressing.  Each gload_lds: wave-uniform LDS base +
  // lane*16B linear; global source pre-swizzled so LDS slot s of row r
  // holds logical k-chunk s ^ (r&7).
  const int kswz = (l7 ^ l3) * 8;                          // elems
  const int rA0 = wv * 8 + l3;                             // A stage row (mod 64)
  const int rB0 = (wv >> 2) * 64 + (wv & 3) * 8 + l3;      // B stage row
  const u16* baseA = X + (size_t)(m0 + rA0) * 2048 + kswz;
  const u16* baseB = W + (size_t)(n0 + rB0) * 2048 + kswz;

  // ---- compute-side read bases (swizzled chunk = (kk*4+fq) ^ (row&7)).
  const int cx = fm & 7;
  const int aRd = (wm * 128 + fm) * 64;   // + h*4096 + mi*1024 + chunk*8
  const int bRd = (wn * 64 + fm) * 64;    // + h*2048 + nj*1024 + chunk*8

  const f32x4 zero = {0.f, 0.f, 0.f, 0.f};
  f32x4 acc[8][4];
#pragma unroll
  for (int i = 0; i < 8; i++)
#pragma unroll
    for (int j = 0; j < 4; j++) acc[i][j] = zero;

  short8 a[4][2], bl[2][2], bh[2][2];

// stage one half-tile (16 KB = 2 gloads/wave).  half: 0=alpha, 1=beta.
#define STAGE_A(buf, half, tt) do {                                        \
    const u16* s_ = baseA + (size_t)(tt) * 64 + (half) * 131072;           \
    u16* d_ = &Al[buf][wv * 512 + (half) * 4096];                          \
    gload_lds16(s_, d_);                                                   \
    gload_lds16(s_ + 262144, d_ + 8192);                                   \
  } while (0)
#define STAGE_B(buf, half, tt) do {                                        \
    const u16* s_ = baseB + (size_t)(tt) * 64 + (half) * 65536;            \
    u16* d_ = &Bl[buf][(wv >> 2) * 4096 + (wv & 3) * 512 + (half) * 2048]; \
    gload_lds16(s_, d_);                                                   \
    gload_lds16(s_ + 262144, d_ + 8192);                                   \
  } while (0)

// quadrant register loads (static indices only)
#define RD_A(buf, h) do {                                                  \
    _Pragma("unroll") for (int mi = 0; mi < 4; mi++)                       \
    _Pragma("unroll") for (int kk = 0; kk < 2; kk++)                       \
      a[mi][kk] = *(const short8*)&Al[buf][aRd + (h) * 4096 + mi * 1024 +  \
                                           ((((kk << 2) | fq) ^ cx) * 8)]; \
  } while (0)
#define RD_B(buf, h, bb) do {                                              \
    _Pragma("unroll") for (int nj = 0; nj < 2; nj++)                       \
    _Pragma("unroll") for (int kk = 0; kk < 2; kk++)                       \
      bb[nj][kk] = *(const short8*)&Bl[buf][bRd + (h) * 2048 + nj * 1024 + \
                                            ((((kk << 2) | fq) ^ cx) * 8)];\
  } while (0)

#define MM(R, Cb, bb) do {                                                 \
    __builtin_amdgcn_s_setprio(1);                                         \
    _Pragma("unroll") for (int mi = 0; mi < 4; mi++)                       \
    _Pragma("unroll") for (int nj = 0; nj < 2; nj++)                       \
    _Pragma("unroll") for (int kk = 0; kk < 2; kk++)                       \
      acc[(R) + mi][(Cb) + nj] = __builtin_amdgcn_mfma_f32_16x16x32_bf16(  \
          a[mi][kk], bb[nj][kk], acc[(R) + mi][(Cb) + nj], 0, 0, 0);       \
    __builtin_amdgcn_s_setprio(0);                                         \
  } while (0)

#define BAR1_LGKM() do {                                                   \
    asm volatile("" ::: "memory");                                         \
    __builtin_amdgcn_s_barrier();                                          \
    asm volatile("s_waitcnt lgkmcnt(0)" ::: "memory");                     \
    __builtin_amdgcn_sched_barrier(0);                                     \
  } while (0)
#define BAR2(N) do {                                                       \
    asm volatile("s_waitcnt vmcnt(" #N ")" ::: "memory");                  \
    __builtin_amdgcn_s_barrier();                                          \
    asm volatile("" ::: "memory");                                         \
  } while (0)

  // ---- prologue: stage tile 0 in consumption order Aa, Ba, Bb, Ab.
  STAGE_A(0, 0, 0);
  STAGE_B(0, 0, 0);
  STAGE_B(0, 1, 0);
  STAGE_A(0, 1, 0);
  asm volatile("s_waitcnt vmcnt(4)" ::: "memory");  // Aa,Ba(0) landed
  __builtin_amdgcn_s_barrier();
  asm volatile("" ::: "memory");

  // ---- main loop: 31 tiles with prefetch of tile kt+1 ----
  for (int kt = 0; kt < 31; ++kt) {
    const int c = kt & 1, o = c ^ 1;
    // phase 0: quadrant (miL, njL); stage Aa(kt+1)
    RD_A(c, 0);
    RD_B(c, 0, bl);
    STAGE_A(o, 0, kt + 1);
    BAR1_LGKM();
    MM(0, 0, bl);
    BAR2(4);
    // phase 1: quadrant (miL, njH); stage Ba(kt+1)
    RD_B(c, 1, bh);
    STAGE_B(o, 0, kt + 1);
    BAR1_LGKM();
    MM(0, 2, bh);
    BAR2(4);
    // phase 2: quadrant (miH, njL); stage Bb(kt+1)
    RD_A(c, 1);
    STAGE_B(o, 1, kt + 1);
    BAR1_LGKM();
    MM(4, 0, bl);
    BAR2(4);
    // phase 3: quadrant (miH, njH); stage Ab(kt+1)
    STAGE_A(o, 1, kt + 1);
    BAR1_LGKM();
    MM(4, 2, bh);
    BAR2(4);
  }

  // ---- tail: tile 31 (buf 1), drain 4 -> 2 -> 0
  {
    RD_A(1, 0);
    RD_B(1, 0, bl);
    BAR1_LGKM();
    MM(0, 0, bl);
    BAR2(2);                 // Bb(31) landed
    RD_B(1, 1, bh);
    BAR1_LGKM();
    MM(0, 2, bh);
    BAR2(0);                 // Ab(31) landed
    RD_A(1, 1);
    BAR1_LGKM();
    MM(4, 0, bl);
    MM(4, 2, bh);
  }

  // ---- epilogue: bias + bf16 convert + batch-interleaved scatter
  float bn[4];
#pragma unroll
  for (int j = 0; j < 4; j++) bn[j] = bias[n0 + wn * 64 + j * 16 + fm];

#pragma unroll
  for (int mi = 0; mi < 8; mi++) {
#pragma unroll
    for (int r = 0; r < 4; r++) {
      int mg = m0 + wm * 128 + mi * 16 + fq * 4 + r;  // C row = quad*4 + reg
      unsigned bb, idx, base;
      if (mg < 24576) { bb = (unsigned)mg / 3u; idx = (unsigned)mg - bb * 3u; base = 0u; }
      else { unsigned mt = (unsigned)mg - 24576u; bb = mt / 3u; idx = mt - bb * 3u; base = 6u; }
      size_t rowbase = (size_t)bb * 12288 + (size_t)(base + idx) * 1024;
#pragma unroll
      for (int j = 0; j < 4; j++) {
        int ng = n0 + wn * 64 + j * 16 + fm;          // C col = lane&15
        size_t pos = rowbase + ((ng & 1024) ? 3072 : 0) + (ng & 1023);
        QK[pos] = f2bf(acc[mi][j][r] + bn[j]);
      }
    }
  }
#undef STAGE_A
#undef STAGE_B
#undef RD_A
#undef RD_B
#undef MM
#undef BAR1_LGKM
#undef BAR2
}

// ---- kernel 3: fused logits -> softmax -> j_lin -> bilinear -> outputs ----
// One block (256 thr) per batch. Reads its 12x1024 bf16 QK block (aliased with
// out_i region it later overwrites; ordering enforced by data deps + barrier).
__global__ __launch_bounds__(256) void fuse_out(
    const float* __restrict__ img, const float* __restrict__ text,
    const float* __restrict__ Wj, const float* __restrict__ bjp,
    const float* __restrict__ Wb, float* __restrict__ out) {
  const int t = threadIdx.x;
  const int lane = t & 63;
  const int wv = t >> 6;
  const int b = blockIdx.x;

  const uint2* qkp = (const uint2*)((const char*)out + (size_t)b * 24576);

  // each thread: 4 consecutive k of each of the 12 rows
  float R[12][4];
#pragma unroll
  for (int r = 0; r < 12; r++) {
    uint2 u = qkp[r * 256 + t];
    R[r][0] = bflo(u.x); R[r][1] = bfhi(u.x);
    R[r][2] = bflo(u.y); R[r][3] = bfhi(u.y);
  }
  float acc[27];
#pragma unroll
  for (int a = 0; a < 27; a++) acc[a] = 0.f;
#pragma unroll
  for (int q = 0; q < 3; q++)
#pragma unroll
    for (int s = 0; s < 3; s++)
#pragma unroll
      for (int j = 0; j < 4; j++) {
        acc[q * 3 + s]      += R[q][j]     * R[9 + s][j];  // it: Qi.Kt
        acc[9 + q * 3 + s]  += R[q][j]     * R[3 + s][j];  // ii: Qi.Ki
        acc[18 + q * 3 + s] += R[6 + q][j] * R[9 + s][j];  // tt: Qt.Kt
      }
  // wave allreduce then cross-wave via LDS
#pragma unroll
  for (int a = 0; a < 27; a++) {
    float v = acc[a];
#pragma unroll
    for (int off = 32; off > 0; off >>= 1) v += __shfl_xor(v, off, 64);
    acc[a] = v;
  }
  __shared__ float red[4][27];
  if (lane == 0) {
#pragma unroll
    for (int a = 0; a < 27; a++) red[wv][a] = acc[a];
  }
  __syncthreads();  // also fences: all QK loads precede the out stores below
  float S[27];
#pragma unroll
  for (int a = 0; a < 27; a++) S[a] = red[0][a] + red[1][a] + red[2][a] + red[3][a];

  // softmax over s, then * 1/sqrt(1024)
  float P[27];
#pragma unroll
  for (int m = 0; m < 3; m++)
#pragma unroll
    for (int q = 0; q < 3; q++) {
      int o0 = m * 9 + q * 3;
      float x = S[o0], y = S[o0 + 1], z = S[o0 + 2];
      float mx = fmaxf(x, fmaxf(y, z));
      float e0 = __expf(x - mx), e1 = __expf(y - mx), e2 = __expf(z - mx);
      float inv = 0.03125f / (e0 + e1 + e2);
      P[o0] = e0 * inv; P[o0 + 1] = e1 * inv; P[o0 + 2] = e2 * inv;
    }
  // j_lin on each map: J[map][q][o] = bj[o] + sum_s Wj[o,s]*P[map][q][s]
  float J[3][3][3];
#pragma unroll
  for (int m = 0; m < 3; m++)
#pragma unroll
    for (int q = 0; q < 3; q++)
#pragma unroll
      for (int o = 0; o < 3; o++)
        J[m][q][o] = bjp[o] + Wj[o * 3 + 0] * P[m * 9 + q * 3 + 0]
                            + Wj[o * 3 + 1] * P[m * 9 + q * 3 + 1]
                            + Wj[o * 3 + 2] * P[m * 9 + q * 3 + 2];
  // bilinear: ai = B(j_it, j_ii), at = B(j_it, j_tt)
  float ai[3][3], at[3][3];
#pragma unroll
  for (int q = 0; q < 3; q++)
#pragma unroll
    for (int o = 0; o < 3; o++) {
      float s1 = 0.f, s2 = 0.f;
#pragma unroll
      for (int i = 0; i < 3; i++) {
        float a1 = J[0][q][i];
#pragma unroll
        for (int j = 0; j < 3; j++) {
          float w = Wb[(o * 3 + i) * 3 + j];
          s1 += a1 * w * J[1][q][j];
          s2 += a1 * w * J[2][q][j];
        }
      }
      ai[q][o] = s1; at[q][o] = s2;
    }

  // outputs: out_i[q,d] = sum_s ai[q][s]*img[s,d] (fp32 inputs), same for text
  const float4* im4 = (const float4*)(img + (size_t)b * 6144);
  const float4* tx4 = (const float4*)(text + (size_t)b * 6144);
  float4* oi4 = (float4*)out + (size_t)b * 1536;
  float4* ot4 = (float4*)out + 12582912 + (size_t)b * 1536;
#pragma unroll
  for (int rep = 0; rep < 2; rep++) {
    int col = rep * 256 + t;
    float4 x0 = im4[col], x1 = im4[512 + col], x2 = im4[1024 + col];
    float4 y0 = tx4[col], y1 = tx4[512 + col], y2 = tx4[1024 + col];
#pragma unroll
    for (int q = 0; q < 3; q++) {
      float4 o1, o2;
      o1.x = ai[q][0] * x0.x + ai[q][1] * x1.x + ai[q][2] * x2.x;
      o1.y = ai[q][0] * x0.y + ai[q][1] * x1.y + ai[q][2] * x2.y;
      o1.z = ai[q][0] * x0.z + ai[q][1] * x1.z + ai[q][2] * x2.z;
      o1.w = ai[q][0] * x0.w + ai[q][1] * x1.w + ai[q][2] * x2.w;
      oi4[q * 512 + col] = o1;
      o2.x = at[q][0] * y0.x + at[q][1] * y1.x + at[q][2] * y2.x;
      o2.y = at[q][0] * y0.y + at[q][1] * y1.y + at[q][2] * y2.y;
      o2.z = at[q][0] * y0.z + at[q][1] * y1.z + at[q][2] * y2.z;
      o2.w = at[q][0] * y0.w + at[q][1] * y1.w + at[q][2] * y2.w;
      ot4[q * 512 + col] = o2;
    }
  }
}

// ---- launch ---------------------------------------------------------------
extern "C" void kernel_launch(void* const* d_in, const int* in_sizes, int n_in,
                              void* d_out, int out_size, void* d_ws, size_t ws_size,
                              hipStream_t stream) {
  const float* img  = (const float*)d_in[0];
  const float* text = (const float*)d_in[1];
  const float* Wq   = (const float*)d_in[2];
  const float* bq   = (const float*)d_in[3];
  const float* Wk   = (const float*)d_in[4];
  const float* bk   = (const float*)d_in[5];
  const float* Wj   = (const float*)d_in[6];
  const float* bj   = (const float*)d_in[7];
  const float* Wbil = (const float*)d_in[8];
  float* out = (float*)d_out;

  // workspace: Wcat bf16 (8,388,608 B) + bcat f32 (8 KB)  => needs ~8.4 MB
  u16* Wcat = (u16*)d_ws;
  float* bcat = (float*)((char*)d_ws + 8388608);
  // d_out second half hosts X=[img;text] bf16; first half hosts QK bf16
  u16* Xbf = (u16*)(out + 50331648);
  u16* QK  = (u16*)out;

  convert_all<<<102402, 256, 0, stream>>>(
      (const float4*)img, (const float4*)text, (const float4*)Wq,
      (const float4*)Wk, (const float4*)bq, (const float4*)bk,
      (ushort4*)Xbf, (ushort4*)Wcat, (float4*)bcat);

  // 1536 blocks = 192 m-tiles x 8 n-tiles (swizzled in-kernel, XCD-aware)
  gemm_qk<<<1536, 512, 0, stream>>>(Xbf, Wcat, bcat, QK);

  fuse_out<<<8192, 256, 0, stream>>>(img, text, Wj, bj, Wbil, out);
}